// Round 1
// baseline (4759.576 us; speedup 1.0000x reference)
//
#include <hip/hip_runtime.h>
#include <hip/hip_bf16.h>

// Problem constants (fixed by reference)
#define BB   2
#define NNODE 4096
#define DD   128
#define KK   32
#define CFX  16
#define EIX  257     // 2*D+1
#define H1X  514     // 2*EI
#define H1P  576     // padded hidden1 (4 quarters of 144, 16B-aligned rows)
#define QTR  144
#define NCHK 9       // 9 chunks of 16 units per quarter
#define C1X  64      // 4*CF
#define NHID 256     // 2*D
#define NINX 144     // D+CF

// ---------------------------------------------------------------- prep: pad weights
__global__ void prep_kernel(const float* __restrict__ We1, const float* __restrict__ be1,
                            const float* __restrict__ We2,
                            float* __restrict__ We1p, float* __restrict__ be1p,
                            float* __restrict__ We2p) {
    int tid = blockIdx.x * 256 + threadIdx.x;
    int stride = gridDim.x * 256;
    for (int i = tid; i < EIX * H1P; i += stride) {
        int c = i / H1P, u = i - c * H1P;
        We1p[i] = (u < H1X) ? We1[c * H1X + u] : 0.f;
    }
    for (int i = tid; i < H1P; i += stride) be1p[i] = (i < H1X) ? be1[i] : 0.f;
    for (int i = tid; i < H1P * CFX; i += stride) {
        int u = i >> 4;
        We2p[i] = (u < H1X) ? We2[i] : 0.f;
    }
}

// ---------------------------------------------------------------- kNN (block = one query row)
__global__ __launch_bounds__(256) void knn_kernel(const float* __restrict__ x,
                                                  int* __restrict__ idx_o,
                                                  float* __restrict__ relk_o,
                                                  float* __restrict__ distk_o) {
    __shared__ float sd[NNODE];
    __shared__ unsigned long long wred[4];
    __shared__ int swin[KK];
    const int t = threadIdx.x;
    const int gn = blockIdx.x;             // b*N + i
    const int b = gn >> 12, i = gn & 4095;
    const float* xb = x + (size_t)b * NNODE * 3;
    const float xi0 = xb[3 * i], xi1 = xb[3 * i + 1], xi2 = xb[3 * i + 2];
    for (int j = t; j < NNODE; j += 256) {
        float d0 = __fsub_rn(xi0, xb[3 * j]);
        float d1 = __fsub_rn(xi1, xb[3 * j + 1]);
        float d2 = __fsub_rn(xi2, xb[3 * j + 2]);
        sd[j] = __fadd_rn(__fadd_rn(__fmul_rn(d0, d0), __fmul_rn(d1, d1)), __fmul_rn(d2, d2));
    }
    __syncthreads();
    const int wv = t >> 6, ln = t & 63;
    for (int k = 0; k < KK; ++k) {
        unsigned long long best = ~0ull;
        for (int j = t; j < NNODE; j += 256) {
            unsigned long long key = ((unsigned long long)__float_as_uint(sd[j]) << 32) | (unsigned)j;
            best = key < best ? key : best;
        }
        #pragma unroll
        for (int off = 32; off > 0; off >>= 1) {
            unsigned long long o = __shfl_xor(best, off, 64);
            best = o < best ? o : best;
        }
        if (ln == 0) wred[wv] = best;
        __syncthreads();
        if (t == 0) {
            unsigned long long r0 = wred[0];
            #pragma unroll
            for (int w2 = 1; w2 < 4; ++w2) { unsigned long long o = wred[w2]; r0 = o < r0 ? o : r0; }
            int jw = (int)(r0 & 0xffffffffu);
            swin[k] = jw;
            sd[jw] = 3.0e38f;
        }
        __syncthreads();
    }
    if (t < KK) {
        int j = swin[t];
        size_t eo = (size_t)gn * KK + t;
        idx_o[eo] = j;
        float r0 = __fsub_rn(xi0, xb[3 * j]);
        float r1 = __fsub_rn(xi1, xb[3 * j + 1]);
        float r2 = __fsub_rn(xi2, xb[3 * j + 2]);
        relk_o[eo * 3 + 0] = r0;
        relk_o[eo * 3 + 1] = r1;
        relk_o[eo * 3 + 2] = r2;
        distk_o[eo] = __fadd_rn(__fadd_rn(__fmul_rn(r0, r0), __fmul_rn(r1, r1)), __fmul_rn(r2, r2));
    }
}

// ---------------------------------------------------------------- edge MLP + coors (block = 4 nodes = 128 edges)
__device__ __forceinline__ float silu_f(float v) { return v * (1.f / (1.f + __expf(-v))); }

#define FMA16(EV, WP) do {                                                   \
    float4 w0_ = (WP)[0], w1_ = (WP)[1], w2_ = (WP)[2], w3_ = (WP)[3];        \
    a[0]  = fmaf((EV), w0_.x, a[0]);  a[1]  = fmaf((EV), w0_.y, a[1]);        \
    a[2]  = fmaf((EV), w0_.z, a[2]);  a[3]  = fmaf((EV), w0_.w, a[3]);        \
    a[4]  = fmaf((EV), w1_.x, a[4]);  a[5]  = fmaf((EV), w1_.y, a[5]);        \
    a[6]  = fmaf((EV), w1_.z, a[6]);  a[7]  = fmaf((EV), w1_.w, a[7]);        \
    a[8]  = fmaf((EV), w2_.x, a[8]);  a[9]  = fmaf((EV), w2_.y, a[9]);        \
    a[10] = fmaf((EV), w2_.z, a[10]); a[11] = fmaf((EV), w2_.w, a[11]);       \
    a[12] = fmaf((EV), w3_.x, a[12]); a[13] = fmaf((EV), w3_.y, a[13]);       \
    a[14] = fmaf((EV), w3_.z, a[14]); a[15] = fmaf((EV), w3_.w, a[15]);       \
} while (0)

__global__ __launch_bounds__(512, 4) void edge_kernel(
    const float* __restrict__ h, const float* __restrict__ x, const int* __restrict__ mask,
    const float* __restrict__ be2,
    const float* __restrict__ Wc1, const float* __restrict__ bc1,
    const float* __restrict__ Wc2, const float* __restrict__ bc2,
    const int* __restrict__ idx, const float* __restrict__ relk, const float* __restrict__ distk,
    const float* __restrict__ We1p, const float* __restrict__ be1p, const float* __restrict__ We2p,
    float* __restrict__ m_i_out, float* __restrict__ coors_out) {
    __shared__ float hi_s[4][129];
    __shared__ __hip_bfloat16 hj_s[128][130];
    __shared__ float dist_s[128];
    __shared__ int j_s[128];
    __shared__ float m_s[128][17];
    __shared__ float cw_s[128];

    const int t = threadIdx.x;
    const int blk = blockIdx.x;
    const int gn0 = blk * 4;           // global node id == b*N + i
    const int b = gn0 >> 12;

    for (int i = t; i < 4 * DD; i += 512) {
        int n = i >> 7, c = i & 127;
        hi_s[n][c] = h[(size_t)(gn0 + n) * DD + c];
    }
    if (t < 128) {
        size_t eo = (size_t)gn0 * KK + t;
        j_s[t] = idx[eo];
        dist_s[t] = distk[eo];
    }
    for (int i = t; i < 128 * CFX; i += 512) {
        int e = i >> 4, f = i & 15;
        m_s[e][f] = be2[f];
    }
    __syncthreads();
    for (int i = t; i < 128 * DD; i += 512) {
        int e = i >> 7, c = i & 127;
        int j = j_s[e];
        hj_s[e][c] = __float2bfloat16(h[((size_t)b * NNODE + j) * DD + c]);
    }
    __syncthreads();

    const int wave = t >> 6, lane = t & 63;
    const int q = wave & 3, eg2 = wave >> 2;
    const int e = eg2 * 64 + lane;
    const int nl = e >> 5;
    const int u0base = q * QTR;

    float pm[16];
    #pragma unroll
    for (int f = 0; f < 16; ++f) pm[f] = 0.f;

    for (int ch = 0; ch < NCHK; ++ch) {
        const int u0 = u0base + ch * 16;
        float a[16];
        {
            const float4* bp = (const float4*)(be1p + u0);
            float4 b0 = bp[0], b1 = bp[1], b2 = bp[2], b3 = bp[3];
            a[0]=b0.x; a[1]=b0.y; a[2]=b0.z; a[3]=b0.w;
            a[4]=b1.x; a[5]=b1.y; a[6]=b1.z; a[7]=b1.w;
            a[8]=b2.x; a[9]=b2.y; a[10]=b2.z; a[11]=b2.w;
            a[12]=b3.x; a[13]=b3.y; a[14]=b3.z; a[15]=b3.w;
        }
        const float* wbase = We1p + u0;
        for (int c = 0; c < 128; ++c) {
            float ev = hi_s[nl][c];
            const float4* wp = (const float4*)(wbase + (size_t)c * H1P);
            FMA16(ev, wp);
        }
        for (int c = 0; c < 128; ++c) {
            float ev = __bfloat162float(hj_s[e][c]);
            const float4* wp = (const float4*)(wbase + (size_t)(c + 128) * H1P);
            FMA16(ev, wp);
        }
        {
            float ev = dist_s[e];
            const float4* wp = (const float4*)(wbase + (size_t)256 * H1P);
            FMA16(ev, wp);
        }
        #pragma unroll
        for (int r = 0; r < 16; ++r) {
            float sh = silu_f(a[r]);
            const float4* qp = (const float4*)(We2p + (size_t)(u0 + r) * CFX);
            float4 q0 = qp[0], q1 = qp[1], q2 = qp[2], q3 = qp[3];
            pm[0]  = fmaf(sh, q0.x, pm[0]);  pm[1]  = fmaf(sh, q0.y, pm[1]);
            pm[2]  = fmaf(sh, q0.z, pm[2]);  pm[3]  = fmaf(sh, q0.w, pm[3]);
            pm[4]  = fmaf(sh, q1.x, pm[4]);  pm[5]  = fmaf(sh, q1.y, pm[5]);
            pm[6]  = fmaf(sh, q1.z, pm[6]);  pm[7]  = fmaf(sh, q1.w, pm[7]);
            pm[8]  = fmaf(sh, q2.x, pm[8]);  pm[9]  = fmaf(sh, q2.y, pm[9]);
            pm[10] = fmaf(sh, q2.z, pm[10]); pm[11] = fmaf(sh, q2.w, pm[11]);
            pm[12] = fmaf(sh, q3.x, pm[12]); pm[13] = fmaf(sh, q3.y, pm[13]);
            pm[14] = fmaf(sh, q3.z, pm[14]); pm[15] = fmaf(sh, q3.w, pm[15]);
        }
    }
    #pragma unroll
    for (int f = 0; f < 16; ++f) atomicAdd(&m_s[e][f], pm[f]);
    __syncthreads();

    // silu on m (post second-linear activation)
    for (int i = t; i < 128 * CFX; i += 512) {
        int ee = i >> 4, f = i & 15;
        m_s[ee][f] = silu_f(m_s[ee][f]);
    }
    __syncthreads();

    // coordinate weight MLP: 4 threads per edge (16 hidden units each)
    {
        const int ee = t >> 2, q4 = t & 3;
        const int u0 = q4 * 16;
        float mm[16];
        #pragma unroll
        for (int f = 0; f < 16; ++f) mm[f] = m_s[ee][f];
        float h2[16];
        {
            const float4* bp = (const float4*)(bc1 + u0);
            float4 b0 = bp[0], b1 = bp[1], b2 = bp[2], b3 = bp[3];
            h2[0]=b0.x; h2[1]=b0.y; h2[2]=b0.z; h2[3]=b0.w;
            h2[4]=b1.x; h2[5]=b1.y; h2[6]=b1.z; h2[7]=b1.w;
            h2[8]=b2.x; h2[9]=b2.y; h2[10]=b2.z; h2[11]=b2.w;
            h2[12]=b3.x; h2[13]=b3.y; h2[14]=b3.z; h2[15]=b3.w;
        }
        #pragma unroll
        for (int f = 0; f < 16; ++f) {
            const float4* wp = (const float4*)(Wc1 + (size_t)f * C1X + u0);
            float4 w0 = wp[0], w1 = wp[1], w2 = wp[2], w3 = wp[3];
            float v = mm[f];
            h2[0]  = fmaf(v, w0.x, h2[0]);  h2[1]  = fmaf(v, w0.y, h2[1]);
            h2[2]  = fmaf(v, w0.z, h2[2]);  h2[3]  = fmaf(v, w0.w, h2[3]);
            h2[4]  = fmaf(v, w1.x, h2[4]);  h2[5]  = fmaf(v, w1.y, h2[5]);
            h2[6]  = fmaf(v, w1.z, h2[6]);  h2[7]  = fmaf(v, w1.w, h2[7]);
            h2[8]  = fmaf(v, w2.x, h2[8]);  h2[9]  = fmaf(v, w2.y, h2[9]);
            h2[10] = fmaf(v, w2.z, h2[10]); h2[11] = fmaf(v, w2.w, h2[11]);
            h2[12] = fmaf(v, w3.x, h2[12]); h2[13] = fmaf(v, w3.y, h2[13]);
            h2[14] = fmaf(v, w3.z, h2[14]); h2[15] = fmaf(v, w3.w, h2[15]);
        }
        float cw = 0.f;
        const float4* cp = (const float4*)(Wc2 + u0);
        float4 c0 = cp[0], c1 = cp[1], c2 = cp[2], c3 = cp[3];
        const float wv[16] = {c0.x,c0.y,c0.z,c0.w, c1.x,c1.y,c1.z,c1.w,
                              c2.x,c2.y,c2.z,c2.w, c3.x,c3.y,c3.z,c3.w};
        #pragma unroll
        for (int r = 0; r < 16; ++r) cw = fmaf(silu_f(h2[r]), wv[r], cw);
        cw += __shfl_xor(cw, 1, 64);
        cw += __shfl_xor(cw, 2, 64);
        if (q4 == 0) {
            cw += bc2[0];
            int gnode = gn0 + (ee >> 5);
            int mi = mask[gnode];
            int mj = mask[b * NNODE + j_s[ee]];
            cw_s[ee] = (mi != 0 && mj != 0) ? cw : 0.f;
        }
    }
    __syncthreads();

    if (t < 64) {
        int n = t >> 4, f = t & 15;
        float s = 0.f;
        #pragma unroll
        for (int k2 = 0; k2 < 32; ++k2) s += m_s[n * 32 + k2][f];
        m_i_out[(size_t)(gn0 + n) * CFX + f] = s;
    } else if (t < 76) {
        int r = t - 64;
        int n = r / 3, c = r - n * 3;
        const float* rp = relk + ((size_t)gn0 * KK + n * 32) * 3 + c;
        float s = 0.f;
        #pragma unroll
        for (int k2 = 0; k2 < 32; ++k2) s = fmaf(cw_s[n * 32 + k2], rp[k2 * 3], s);
        coors_out[(size_t)(gn0 + n) * 3 + c] = s + x[(size_t)(gn0 + n) * 3 + c];
    }
}

// ---------------------------------------------------------------- node MLP (block = 4 nodes)
__global__ __launch_bounds__(256) void node_kernel(
    const float* __restrict__ h, const float* __restrict__ m_i,
    const float* __restrict__ Wn1, const float* __restrict__ bn1,
    const float* __restrict__ Wn2, const float* __restrict__ bn2,
    float* __restrict__ node_out) {
    __shared__ float nin[4][NINX + 1];
    __shared__ float hid[4][NHID + 1];
    const int t = threadIdx.x;
    const int gn0 = blockIdx.x * 4;
    for (int i = t; i < 4 * DD; i += 256) {
        int n = i >> 7, c = i & 127;
        nin[n][c] = h[(size_t)(gn0 + n) * DD + c];
    }
    if (t < 64) {
        int n = t >> 4, f = t & 15;
        nin[n][DD + f] = m_i[(size_t)(gn0 + n) * CFX + f];
    }
    __syncthreads();
    {
        const int u = t;
        float bv = bn1[u];
        float a0 = bv, a1 = bv, a2 = bv, a3 = bv;
        for (int c = 0; c < NINX; ++c) {
            float w = Wn1[(size_t)c * NHID + u];
            a0 = fmaf(nin[0][c], w, a0);
            a1 = fmaf(nin[1][c], w, a1);
            a2 = fmaf(nin[2][c], w, a2);
            a3 = fmaf(nin[3][c], w, a3);
        }
        hid[0][u] = silu_f(a0);
        hid[1][u] = silu_f(a1);
        hid[2][u] = silu_f(a2);
        hid[3][u] = silu_f(a3);
    }
    __syncthreads();
    {
        const int d = t & 127, n2 = t >> 7;   // n2 in {0,1} -> nodes n2 and n2+2
        float bv = bn2[d];
        float a0 = bv, a1 = bv;
        for (int uu = 0; uu < NHID; ++uu) {
            float w = Wn2[(size_t)uu * DD + d];
            a0 = fmaf(hid[n2][uu], w, a0);
            a1 = fmaf(hid[n2 + 2][uu], w, a1);
        }
        node_out[(size_t)(gn0 + n2) * DD + d] = a0 + nin[n2][d];
        node_out[(size_t)(gn0 + n2 + 2) * DD + d] = a1 + nin[n2 + 2][d];
    }
}

// ---------------------------------------------------------------- launch
extern "C" void kernel_launch(void* const* d_in, const int* in_sizes, int n_in,
                              void* d_out, int out_size, void* d_ws, size_t ws_size,
                              hipStream_t stream) {
    const float* h   = (const float*)d_in[0];
    const float* x   = (const float*)d_in[1];
    const int*   mask= (const int*)d_in[2];
    const float* We1 = (const float*)d_in[3];
    const float* be1 = (const float*)d_in[4];
    const float* We2 = (const float*)d_in[5];
    const float* be2 = (const float*)d_in[6];
    const float* Wc1 = (const float*)d_in[7];
    const float* bc1 = (const float*)d_in[8];
    const float* Wc2 = (const float*)d_in[9];
    const float* bc2 = (const float*)d_in[10];
    const float* Wn1 = (const float*)d_in[11];
    const float* bn1 = (const float*)d_in[12];
    const float* Wn2 = (const float*)d_in[13];
    const float* bn2 = (const float*)d_in[14];

    float* node_out  = (float*)d_out;
    float* coors_out = node_out + (size_t)BB * NNODE * DD;

    // workspace layout (all 16B-aligned): ~6.3 MB total
    char* ws = (char*)d_ws;
    int*   idx   = (int*)ws;    ws += (size_t)BB * NNODE * KK * 4;
    float* relk  = (float*)ws;  ws += (size_t)BB * NNODE * KK * 3 * 4;
    float* distk = (float*)ws;  ws += (size_t)BB * NNODE * KK * 4;
    float* m_i   = (float*)ws;  ws += (size_t)BB * NNODE * CFX * 4;
    float* We1p  = (float*)ws;  ws += (size_t)EIX * H1P * 4;
    float* be1p  = (float*)ws;  ws += (size_t)H1P * 4;
    float* We2p  = (float*)ws;  ws += (size_t)H1P * CFX * 4;

    prep_kernel<<<64, 256, 0, stream>>>(We1, be1, We2, We1p, be1p, We2p);
    knn_kernel<<<BB * NNODE, 256, 0, stream>>>(x, idx, relk, distk);
    edge_kernel<<<BB * NNODE / 4, 512, 0, stream>>>(h, x, mask, be2, Wc1, bc1, Wc2, bc2,
                                                    idx, relk, distk, We1p, be1p, We2p,
                                                    m_i, coors_out);
    node_kernel<<<BB * NNODE / 4, 256, 0, stream>>>(h, m_i, Wn1, bn1, Wn2, bn2, node_out);
}

// Round 2
// 632.595 us; speedup vs baseline: 7.5239x; 7.5239x over previous
//
#include <hip/hip_runtime.h>

// Problem constants (fixed by reference)
#define BB    2
#define NNODE 4096
#define DD    128
#define KK    32
#define CFX   16
#define NHID  256    // 2*D
#define NINX  144    // D+CF

typedef __attribute__((ext_vector_type(8))) short bf16x8;
typedef __attribute__((ext_vector_type(4))) float f32x4;

__device__ __forceinline__ unsigned short f2bf(float f) {
    unsigned int u = __float_as_uint(f);
    unsigned int r = (u + 0x7fffu + ((u >> 16) & 1u)) >> 16;
    return (unsigned short)r;
}
__device__ __forceinline__ float silu_f(float v) { return v * (1.f / (1.f + __expf(-v))); }

// ---------------------------------------------------------------- prep: pack weights into MFMA fragment layout
// W1pack[ks 0..8][nb 0..35][lane 0..63][i 0..7] (bf16):
//   n = nb*16 + (lane&15); k = ks*32 + 8*(lane>>4) + i; val = (k<257 && n<514) ? We1[k][n] : 0
// W2p2[wn 0..3][ks2 0..4][lane][i] (bf16):
//   f = lane&15; g = lane>>4; nloc = ks2*32 + 16*(i>>2) + 4*g + (i&3); ng = wn*144 + nloc
//   val = (nloc<144 && ng<514) ? We2[ng][f] : 0
__global__ void prep_kernel(const float* __restrict__ We1, const float* __restrict__ We2,
                            unsigned short* __restrict__ W1pack, unsigned short* __restrict__ W2p2) {
    int tid = blockIdx.x * 256 + threadIdx.x;
    int stride = gridDim.x * 256;
    for (int p = tid; p < 9 * 36 * 64 * 8; p += stride) {
        int i = p & 7, lane = (p >> 3) & 63, rest = p >> 9;
        int nb = rest % 36, ks = rest / 36;
        int n = nb * 16 + (lane & 15);
        int k = ks * 32 + 8 * (lane >> 4) + i;
        W1pack[p] = (k < 257 && n < 514) ? f2bf(We1[k * 514 + n]) : (unsigned short)0;
    }
    for (int p = tid; p < 4 * 5 * 64 * 8; p += stride) {
        int i = p & 7, lane = (p >> 3) & 63, rest = p >> 9;
        int ks2 = rest % 5, wn = rest / 5;
        int g = lane >> 4, f = lane & 15;
        int nloc = ks2 * 32 + ((i >> 2) * 16) + 4 * g + (i & 3);
        int ng = wn * 144 + nloc;
        W2p2[p] = (nloc < 144 && ng < 514) ? f2bf(We2[ng * 16 + f]) : (unsigned short)0;
    }
}

// ---------------------------------------------------------------- kNN (unchanged from R1 — passed)
__global__ __launch_bounds__(256) void knn_kernel(const float* __restrict__ x,
                                                  int* __restrict__ idx_o,
                                                  float* __restrict__ relk_o,
                                                  float* __restrict__ distk_o) {
    __shared__ float sd[NNODE];
    __shared__ unsigned long long wred[4];
    __shared__ int swin[KK];
    const int t = threadIdx.x;
    const int gn = blockIdx.x;
    const int b = gn >> 12, i = gn & 4095;
    const float* xb = x + (size_t)b * NNODE * 3;
    const float xi0 = xb[3 * i], xi1 = xb[3 * i + 1], xi2 = xb[3 * i + 2];
    for (int j = t; j < NNODE; j += 256) {
        float d0 = __fsub_rn(xi0, xb[3 * j]);
        float d1 = __fsub_rn(xi1, xb[3 * j + 1]);
        float d2 = __fsub_rn(xi2, xb[3 * j + 2]);
        sd[j] = __fadd_rn(__fadd_rn(__fmul_rn(d0, d0), __fmul_rn(d1, d1)), __fmul_rn(d2, d2));
    }
    __syncthreads();
    const int wv = t >> 6, ln = t & 63;
    for (int k = 0; k < KK; ++k) {
        unsigned long long best = ~0ull;
        for (int j = t; j < NNODE; j += 256) {
            unsigned long long key = ((unsigned long long)__float_as_uint(sd[j]) << 32) | (unsigned)j;
            best = key < best ? key : best;
        }
        #pragma unroll
        for (int off = 32; off > 0; off >>= 1) {
            unsigned long long o = __shfl_xor(best, off, 64);
            best = o < best ? o : best;
        }
        if (ln == 0) wred[wv] = best;
        __syncthreads();
        if (t == 0) {
            unsigned long long r0 = wred[0];
            #pragma unroll
            for (int w2 = 1; w2 < 4; ++w2) { unsigned long long o = wred[w2]; r0 = o < r0 ? o : r0; }
            int jw = (int)(r0 & 0xffffffffu);
            swin[k] = jw;
            sd[jw] = 3.0e38f;
        }
        __syncthreads();
    }
    if (t < KK) {
        int j = swin[t];
        size_t eo = (size_t)gn * KK + t;
        idx_o[eo] = j;
        float r0 = __fsub_rn(xi0, xb[3 * j]);
        float r1 = __fsub_rn(xi1, xb[3 * j + 1]);
        float r2 = __fsub_rn(xi2, xb[3 * j + 2]);
        relk_o[eo * 3 + 0] = r0;
        relk_o[eo * 3 + 1] = r1;
        relk_o[eo * 3 + 2] = r2;
        distk_o[eo] = __fadd_rn(__fadd_rn(__fmul_rn(r0, r0), __fmul_rn(r1, r1)), __fmul_rn(r2, r2));
    }
}

// ---------------------------------------------------------------- edge MLP via MFMA + coors (block = 4 nodes = 128 edges)
// GEMM1 (transposed): D[n=576][edge=128] = W1^T (A-op, prepacked) x E^T (B-op from LDS), K=288
// GEMM2: m^T[f=16][edge] = W2^T (A-op prepacked per-wn) x silu(D)^T (B-op straight from acc regs)
__global__ __launch_bounds__(512, 2) void edge_kernel(
    const float* __restrict__ h, const float* __restrict__ x, const int* __restrict__ mask,
    const float* __restrict__ be1, const float* __restrict__ be2,
    const float* __restrict__ Wc1, const float* __restrict__ bc1,
    const float* __restrict__ Wc2, const float* __restrict__ bc2,
    const int* __restrict__ idx, const float* __restrict__ relk, const float* __restrict__ distk,
    const unsigned short* __restrict__ W1pack, const unsigned short* __restrict__ W2p2,
    float* __restrict__ m_i_out, float* __restrict__ coors_out)
{
    __shared__ unsigned short E2[128][168];   // per-edge: h_j (cols 0..127), dist (128), zeros (129..159), pad
    __shared__ unsigned short hi_s[4][136];   // per-node h_i (k 0..127)
    __shared__ float be1s[576];
    __shared__ int   j_s[128];
    __shared__ float cw_s[128];
    __shared__ float m_s[128][17];

    const int t = threadIdx.x;
    const int gn0 = blockIdx.x * 4;
    const int b = gn0 >> 12;
    const int wave = t >> 6, lane = t & 63;
    const int l15 = lane & 15, g = lane >> 4;
    const int wn = wave >> 1, we = wave & 1;   // wn: n-slice (144 cols), we: edge-half (64 edges)

    // ---- init phase
    if (t < 128) {
        size_t eo = (size_t)gn0 * KK + t;
        j_s[t] = idx[eo];
        float dv = distk[eo];
        ushort2* p = (ushort2*)&E2[t][128];
        p[0] = make_ushort2(f2bf(dv), 0);
        #pragma unroll
        for (int z = 1; z < 20; ++z) p[z] = make_ushort2(0, 0);   // zeros through col 167
    }
    {
        int n = t >> 7, c = t & 127;
        hi_s[n][c] = f2bf(h[(size_t)(gn0 + n) * DD + c]);
    }
    for (int i = t; i < 576; i += 512) be1s[i] = (i < 514) ? be1[i] : 0.f;
    for (int i = t; i < 128 * 17; i += 512) ((float*)m_s)[i] = 0.f;
    __syncthreads();

    // ---- gather h_j into E2 (bf16)
    for (int q = t; q < 4096; q += 512) {
        int e = q >> 5, d4 = q & 31;
        int j = j_s[e];
        float4 v = *(const float4*)(h + ((size_t)b * NNODE + j) * DD + d4 * 4);
        unsigned int lo = (unsigned)f2bf(v.x) | ((unsigned)f2bf(v.y) << 16);
        unsigned int hi = (unsigned)f2bf(v.z) | ((unsigned)f2bf(v.w) << 16);
        *(uint2*)&E2[e][d4 * 4] = make_uint2(lo, hi);
    }
    __syncthreads();

    // ---- GEMM1: acc[nb 0..8][et 0..3], nb = n-tile within wn slice, et = edge-tile within we half
    f32x4 acc[9][4];
    #pragma unroll
    for (int nb = 0; nb < 9; ++nb)
        #pragma unroll
        for (int et = 0; et < 4; ++et)
            #pragma unroll
            for (int r = 0; r < 4; ++r) acc[nb][et][r] = 0.f;

    const bf16x8* W1v = (const bf16x8*)W1pack;
    int erow[4], nodeet[4];
    #pragma unroll
    for (int et = 0; et < 4; ++et) {
        int e = (we * 4 + et) * 16 + l15;
        erow[et] = e;
        nodeet[et] = e >> 5;
    }

    // k-steps 0..3: B operand from hi_s (h_i features, shared per node -> broadcast reads)
    for (int ks = 0; ks < 4; ++ks) {
        bf16x8 bfr[4];
        #pragma unroll
        for (int et = 0; et < 4; ++et)
            bfr[et] = *(const bf16x8*)&hi_s[nodeet[et]][ks * 32 + 8 * g];
        const bf16x8* wp = W1v + (size_t)(ks * 36 + wn * 9) * 64 + lane;
        #pragma unroll
        for (int nb = 0; nb < 9; ++nb) {
            bf16x8 af = wp[nb * 64];
            #pragma unroll
            for (int et = 0; et < 4; ++et)
                acc[nb][et] = __builtin_amdgcn_mfma_f32_16x16x32_bf16(af, bfr[et], acc[nb][et], 0, 0, 0);
        }
    }
    // k-steps 4..8: B operand from E2 (h_j, dist, zero-pad)
    for (int ks = 4; ks < 9; ++ks) {
        bf16x8 bfr[4];
        #pragma unroll
        for (int et = 0; et < 4; ++et)
            bfr[et] = *(const bf16x8*)&E2[erow[et]][(ks - 4) * 32 + 8 * g];
        const bf16x8* wp = W1v + (size_t)(ks * 36 + wn * 9) * 64 + lane;
        #pragma unroll
        for (int nb = 0; nb < 9; ++nb) {
            bf16x8 af = wp[nb * 64];
            #pragma unroll
            for (int et = 0; et < 4; ++et)
                acc[nb][et] = __builtin_amdgcn_mfma_f32_16x16x32_bf16(af, bfr[et], acc[nb][et], 0, 0, 0);
        }
    }

    // ---- silu(acc + be1) in registers
    #pragma unroll
    for (int nb = 0; nb < 9; ++nb) {
        f32x4 bv = *(const f32x4*)&be1s[wn * 144 + nb * 16 + 4 * g];
        #pragma unroll
        for (int et = 0; et < 4; ++et)
            #pragma unroll
            for (int r = 0; r < 4; ++r)
                acc[nb][et][r] = silu_f(acc[nb][et][r] + bv[r]);
    }

    // ---- GEMM2: B operand packed straight from acc (slot (g,i) <-> acc[2*ks2+(i>>2)][i&3]), partial over this wave's n-slice
    f32x4 acc2[4];
    #pragma unroll
    for (int et = 0; et < 4; ++et)
        #pragma unroll
        for (int r = 0; r < 4; ++r) acc2[et][r] = 0.f;

    const bf16x8* W2v = (const bf16x8*)W2p2;
    #pragma unroll
    for (int ks2 = 0; ks2 < 5; ++ks2) {
        bf16x8 a2 = W2v[(size_t)(wn * 5 + ks2) * 64 + lane];
        #pragma unroll
        for (int et = 0; et < 4; ++et) {
            bf16x8 b2;
            #pragma unroll
            for (int i = 0; i < 8; ++i) {
                float v = (ks2 == 4 && i >= 4) ? 0.f : acc[2 * ks2 + (i >> 2)][et][i & 3];
                b2[i] = (short)f2bf(v);
            }
            acc2[et] = __builtin_amdgcn_mfma_f32_16x16x32_bf16(a2, b2, acc2[et], 0, 0, 0);
        }
    }
    // scatter partial m (pre-silu) into m_s; 4 wn-waves sum per cell
    #pragma unroll
    for (int et = 0; et < 4; ++et)
        #pragma unroll
        for (int r = 0; r < 4; ++r)
            atomicAdd(&m_s[erow[et]][4 * g + r], acc2[et][r]);
    __syncthreads();

    // ---- m_ij = silu(sum + be2)
    for (int i = t; i < 128 * CFX; i += 512) {
        int ee = i >> 4, f = i & 15;
        m_s[ee][f] = silu_f(m_s[ee][f] + be2[f]);
    }
    __syncthreads();

    // ---- coordinate-weight MLP: 4 threads per edge (16 hidden units each)
    {
        const int ee = t >> 2, q4 = t & 3;
        const int u0 = q4 * 16;
        float mm[16];
        #pragma unroll
        for (int f = 0; f < 16; ++f) mm[f] = m_s[ee][f];
        float h2[16];
        {
            const float4* bp = (const float4*)(bc1 + u0);
            float4 b0 = bp[0], b1 = bp[1], b2v = bp[2], b3 = bp[3];
            h2[0]=b0.x; h2[1]=b0.y; h2[2]=b0.z; h2[3]=b0.w;
            h2[4]=b1.x; h2[5]=b1.y; h2[6]=b1.z; h2[7]=b1.w;
            h2[8]=b2v.x; h2[9]=b2v.y; h2[10]=b2v.z; h2[11]=b2v.w;
            h2[12]=b3.x; h2[13]=b3.y; h2[14]=b3.z; h2[15]=b3.w;
        }
        #pragma unroll
        for (int f = 0; f < 16; ++f) {
            const float4* wp = (const float4*)(Wc1 + (size_t)f * 64 + u0);
            float4 w0 = wp[0], w1 = wp[1], w2 = wp[2], w3 = wp[3];
            float v = mm[f];
            h2[0]  = fmaf(v, w0.x, h2[0]);  h2[1]  = fmaf(v, w0.y, h2[1]);
            h2[2]  = fmaf(v, w0.z, h2[2]);  h2[3]  = fmaf(v, w0.w, h2[3]);
            h2[4]  = fmaf(v, w1.x, h2[4]);  h2[5]  = fmaf(v, w1.y, h2[5]);
            h2[6]  = fmaf(v, w1.z, h2[6]);  h2[7]  = fmaf(v, w1.w, h2[7]);
            h2[8]  = fmaf(v, w2.x, h2[8]);  h2[9]  = fmaf(v, w2.y, h2[9]);
            h2[10] = fmaf(v, w2.z, h2[10]); h2[11] = fmaf(v, w2.w, h2[11]);
            h2[12] = fmaf(v, w3.x, h2[12]); h2[13] = fmaf(v, w3.y, h2[13]);
            h2[14] = fmaf(v, w3.z, h2[14]); h2[15] = fmaf(v, w3.w, h2[15]);
        }
        float cw = 0.f;
        const float4* cp = (const float4*)(Wc2 + u0);
        float4 c0 = cp[0], c1 = cp[1], c2 = cp[2], c3 = cp[3];
        const float wv[16] = {c0.x,c0.y,c0.z,c0.w, c1.x,c1.y,c1.z,c1.w,
                              c2.x,c2.y,c2.z,c2.w, c3.x,c3.y,c3.z,c3.w};
        #pragma unroll
        for (int r = 0; r < 16; ++r) cw = fmaf(silu_f(h2[r]), wv[r], cw);
        cw += __shfl_xor(cw, 1, 64);
        cw += __shfl_xor(cw, 2, 64);
        if (q4 == 0) {
            cw += bc2[0];
            int gnode = gn0 + (ee >> 5);
            int mi = mask[gnode];
            int mj = mask[b * NNODE + j_s[ee]];
            cw_s[ee] = (mi != 0 && mj != 0) ? cw : 0.f;
        }
    }
    __syncthreads();

    // ---- outputs: m_i (sum over 32 neighbors) and coors
    if (t < 64) {
        int n = t >> 4, f = t & 15;
        float s = 0.f;
        #pragma unroll
        for (int k2 = 0; k2 < 32; ++k2) s += m_s[n * 32 + k2][f];
        m_i_out[(size_t)(gn0 + n) * CFX + f] = s;
    } else if (t < 76) {
        int r = t - 64;
        int n = r / 3, c = r - n * 3;
        const float* rp = relk + ((size_t)gn0 * KK + n * 32) * 3 + c;
        float s = 0.f;
        #pragma unroll
        for (int k2 = 0; k2 < 32; ++k2) s = fmaf(cw_s[n * 32 + k2], rp[k2 * 3], s);
        coors_out[(size_t)(gn0 + n) * 3 + c] = s + x[(size_t)(gn0 + n) * 3 + c];
    }
}

// ---------------------------------------------------------------- node MLP (unchanged from R1 — passed)
__global__ __launch_bounds__(256) void node_kernel(
    const float* __restrict__ h, const float* __restrict__ m_i,
    const float* __restrict__ Wn1, const float* __restrict__ bn1,
    const float* __restrict__ Wn2, const float* __restrict__ bn2,
    float* __restrict__ node_out) {
    __shared__ float nin[4][NINX + 1];
    __shared__ float hid[4][NHID + 1];
    const int t = threadIdx.x;
    const int gn0 = blockIdx.x * 4;
    for (int i = t; i < 4 * DD; i += 256) {
        int n = i >> 7, c = i & 127;
        nin[n][c] = h[(size_t)(gn0 + n) * DD + c];
    }
    if (t < 64) {
        int n = t >> 4, f = t & 15;
        nin[n][DD + f] = m_i[(size_t)(gn0 + n) * CFX + f];
    }
    __syncthreads();
    {
        const int u = t;
        float bv = bn1[u];
        float a0 = bv, a1 = bv, a2 = bv, a3 = bv;
        for (int c = 0; c < NINX; ++c) {
            float w = Wn1[(size_t)c * NHID + u];
            a0 = fmaf(nin[0][c], w, a0);
            a1 = fmaf(nin[1][c], w, a1);
            a2 = fmaf(nin[2][c], w, a2);
            a3 = fmaf(nin[3][c], w, a3);
        }
        hid[0][u] = silu_f(a0);
        hid[1][u] = silu_f(a1);
        hid[2][u] = silu_f(a2);
        hid[3][u] = silu_f(a3);
    }
    __syncthreads();
    {
        const int d = t & 127, n2 = t >> 7;
        float bv = bn2[d];
        float a0 = bv, a1 = bv;
        for (int uu = 0; uu < NHID; ++uu) {
            float w = Wn2[(size_t)uu * DD + d];
            a0 = fmaf(hid[n2][uu], w, a0);
            a1 = fmaf(hid[n2 + 2][uu], w, a1);
        }
        node_out[(size_t)(gn0 + n2) * DD + d] = a0 + nin[n2][d];
        node_out[(size_t)(gn0 + n2 + 2) * DD + d] = a1 + nin[n2 + 2][d];
    }
}

// ---------------------------------------------------------------- launch
extern "C" void kernel_launch(void* const* d_in, const int* in_sizes, int n_in,
                              void* d_out, int out_size, void* d_ws, size_t ws_size,
                              hipStream_t stream) {
    const float* h   = (const float*)d_in[0];
    const float* x   = (const float*)d_in[1];
    const int*   mask= (const int*)d_in[2];
    const float* We1 = (const float*)d_in[3];
    const float* be1 = (const float*)d_in[4];
    const float* We2 = (const float*)d_in[5];
    const float* be2 = (const float*)d_in[6];
    const float* Wc1 = (const float*)d_in[7];
    const float* bc1 = (const float*)d_in[8];
    const float* Wc2 = (const float*)d_in[9];
    const float* bc2 = (const float*)d_in[10];
    const float* Wn1 = (const float*)d_in[11];
    const float* bn1 = (const float*)d_in[12];
    const float* Wn2 = (const float*)d_in[13];
    const float* bn2 = (const float*)d_in[14];

    float* node_out  = (float*)d_out;
    float* coors_out = node_out + (size_t)BB * NNODE * DD;

    // workspace layout (16B-aligned pieces), ~6.1 MB total
    char* ws = (char*)d_ws;
    int*   idx    = (int*)ws;            ws += (size_t)BB * NNODE * KK * 4;       // 1,048,576
    float* relk   = (float*)ws;          ws += (size_t)BB * NNODE * KK * 3 * 4;   // 3,145,728
    float* distk  = (float*)ws;          ws += (size_t)BB * NNODE * KK * 4;       // 1,048,576
    float* m_i    = (float*)ws;          ws += (size_t)BB * NNODE * CFX * 4;      //   524,288
    unsigned short* W1pack = (unsigned short*)ws;  ws += (size_t)9 * 36 * 64 * 8 * 2;  // 331,776
    unsigned short* W2p2   = (unsigned short*)ws;  ws += (size_t)4 * 5 * 64 * 8 * 2;   //  20,480

    prep_kernel<<<256, 256, 0, stream>>>(We1, We2, W1pack, W2p2);
    knn_kernel<<<BB * NNODE, 256, 0, stream>>>(x, idx, relk, distk);
    edge_kernel<<<BB * NNODE / 4, 512, 0, stream>>>(h, x, mask, be1, be2, Wc1, bc1, Wc2, bc2,
                                                    idx, relk, distk, W1pack, W2p2,
                                                    m_i, coors_out);
    node_kernel<<<BB * NNODE / 4, 256, 0, stream>>>(h, m_i, Wn1, bn1, Wn2, bn2, node_out);
}

// Round 3
// 368.570 us; speedup vs baseline: 12.9136x; 1.7164x over previous
//
#include <hip/hip_runtime.h>
#include <hip/hip_bf16.h>

// Problem constants (fixed by reference)
#define BB    2
#define NNODE 4096
#define DD    128
#define KK    32
#define CFX   16
#define NHID  256    // 2*D
#define NINX  144    // D+CF

typedef __attribute__((ext_vector_type(8))) short bf16x8;
typedef __attribute__((ext_vector_type(4))) float f32x4;

__device__ __forceinline__ unsigned short f2bf(float f) {
    __hip_bfloat16 h = __float2bfloat16(f);
    return *reinterpret_cast<unsigned short*>(&h);
}
__device__ __forceinline__ unsigned pk2(float lo, float hi) {
    __hip_bfloat162 v = __float22bfloat162_rn(make_float2(lo, hi));
    return *reinterpret_cast<unsigned*>(&v);
}
__device__ __forceinline__ float silu_f(float v) { return v * (1.f / (1.f + __expf(-v))); }

// ---------------------------------------------------------------- prep: pack weights into MFMA fragment layout
// W1pack[ks 0..8][nb 0..35][lane 0..63][i 0..7] (bf16):
//   n = nb*16 + (lane&15); k = ks*32 + 8*(lane>>4) + i; val = (k<257 && n<514) ? We1[k][n] : 0
// W2p2[wn 0..3][ks2 0..4][lane][i] (bf16):
//   f = lane&15; g = lane>>4; nloc = ks2*32 + 16*(i>>2) + 4*g + (i&3); ng = wn*144 + nloc
//   val = (nloc<144 && ng<514) ? We2[ng][f] : 0
__global__ void prep_kernel(const float* __restrict__ We1, const float* __restrict__ We2,
                            unsigned short* __restrict__ W1pack, unsigned short* __restrict__ W2p2) {
    int tid = blockIdx.x * 256 + threadIdx.x;
    int stride = gridDim.x * 256;
    for (int p = tid; p < 9 * 36 * 64 * 8; p += stride) {
        int i = p & 7, lane = (p >> 3) & 63, rest = p >> 9;
        int nb = rest % 36, ks = rest / 36;
        int n = nb * 16 + (lane & 15);
        int k = ks * 32 + 8 * (lane >> 4) + i;
        W1pack[p] = (k < 257 && n < 514) ? f2bf(We1[k * 514 + n]) : (unsigned short)0;
    }
    for (int p = tid; p < 4 * 5 * 64 * 8; p += stride) {
        int i = p & 7, lane = (p >> 3) & 63, rest = p >> 9;
        int ks2 = rest % 5, wn = rest / 5;
        int g = lane >> 4, f = lane & 15;
        int nloc = ks2 * 32 + ((i >> 2) * 16) + 4 * g + (i & 3);
        int ng = wn * 144 + nloc;
        W2p2[p] = (nloc < 144 && ng < 514) ? f2bf(We2[ng * 16 + f]) : (unsigned short)0;
    }
}

// ---------------------------------------------------------------- kNN v2: radix-select (block = one query row)
#define EQCAP 36
__global__ __launch_bounds__(256) void knn_kernel(const float* __restrict__ x,
                                                  int* __restrict__ idx_o,
                                                  float* __restrict__ relk_o,
                                                  float* __restrict__ distk_o) {
    __shared__ float sd[NNODE];
    __shared__ unsigned hist[256];
    __shared__ unsigned wsum[4];
    __shared__ unsigned sel[2];
    __shared__ unsigned totLs, totEs;
    __shared__ int out_j[KK];
    __shared__ int eqbuf[EQCAP];

    const int t = threadIdx.x;
    const int ln = t & 63, wv = t >> 6;
    const int gn = blockIdx.x;
    const int b = gn >> 12, i = gn & 4095;
    const float* xb = x + (size_t)b * NNODE * 3;
    const float xi0 = xb[3 * i], xi1 = xb[3 * i + 1], xi2 = xb[3 * i + 2];
    #pragma unroll
    for (int s = 0; s < 16; ++s) {
        int j = t + 256 * s;
        float d0 = __fsub_rn(xi0, xb[3 * j]);
        float d1 = __fsub_rn(xi1, xb[3 * j + 1]);
        float d2 = __fsub_rn(xi2, xb[3 * j + 2]);
        sd[j] = __fadd_rn(__fadd_rn(__fmul_rn(d0, d0), __fmul_rn(d1, d1)), __fmul_rn(d2, d2));
    }

    // ---- 4-round radix select over 32-bit dist keys: find T = bits of 32nd-smallest
    unsigned prefix = 0;
    int kk = KK;
    for (int r = 0; r < 4; ++r) {
        const int sh = 24 - 8 * r;
        hist[t] = 0;
        __syncthreads();
        #pragma unroll
        for (int s = 0; s < 16; ++s) {
            unsigned u = __float_as_uint(sd[t + 256 * s]);
            bool ok;
            if (r == 0) ok = true;
            else ok = ((u >> (sh + 8)) == prefix);
            if (ok) atomicAdd(&hist[(u >> sh) & 255], 1u);
        }
        __syncthreads();
        unsigned hv = hist[t];
        // inclusive scan over 256 threads
        unsigned v = hv;
        #pragma unroll
        for (int off = 1; off < 64; off <<= 1) {
            unsigned o = __shfl_up(v, off, 64);
            if (ln >= off) v += o;
        }
        if (ln == 63) wsum[wv] = v;
        __syncthreads();
        unsigned add = 0;
        #pragma unroll
        for (int w = 0; w < 4; ++w) add += (w < wv) ? wsum[w] : 0u;
        unsigned incl = v + add;
        unsigned excl = incl - hv;
        if ((unsigned)kk > excl && (unsigned)kk <= incl) { sel[0] = (unsigned)t; sel[1] = (unsigned)kk - excl; }
        __syncthreads();
        prefix = (prefix << 8) | sel[0];
        kk = (int)sel[1];
        __syncthreads();
    }
    const unsigned T = prefix;

    // ---- deterministic collection: all dist<T, plus smallest-index ties at T
    unsigned cl = 0, ce = 0;
    #pragma unroll
    for (int s = 0; s < 16; ++s) {
        unsigned u = __float_as_uint(sd[t + 256 * s]);
        cl += (u < T);
        ce += (u == T);
    }
    // scan cl
    unsigned v = cl;
    #pragma unroll
    for (int off = 1; off < 64; off <<= 1) {
        unsigned o = __shfl_up(v, off, 64);
        if (ln >= off) v += o;
    }
    if (ln == 63) wsum[wv] = v;
    __syncthreads();
    unsigned add = 0;
    #pragma unroll
    for (int w = 0; w < 4; ++w) add += (w < wv) ? wsum[w] : 0u;
    unsigned exclL = v + add - cl;
    if (t == 255) totLs = v + add;
    __syncthreads();
    // scan ce
    unsigned v2 = ce;
    #pragma unroll
    for (int off = 1; off < 64; off <<= 1) {
        unsigned o = __shfl_up(v2, off, 64);
        if (ln >= off) v2 += o;
    }
    if (ln == 63) wsum[wv] = v2;
    __syncthreads();
    unsigned add2 = 0;
    #pragma unroll
    for (int w = 0; w < 4; ++w) add2 += (w < wv) ? wsum[w] : 0u;
    unsigned exclE = v2 + add2 - ce;
    if (t == 255) totEs = v2 + add2;
    __syncthreads();
    const unsigned totL = totLs, totE = totEs;
    const int need = KK - (int)totL;   // >=1, <= totE by construction of T

    unsigned wl = exclL, we = exclE;
    #pragma unroll
    for (int s = 0; s < 16; ++s) {
        int j = t + 256 * s;
        unsigned u = __float_as_uint(sd[j]);
        if (u < T) { out_j[wl++] = j; }
        else if (u == T) { if (we < EQCAP) eqbuf[we] = j; ++we; }
    }
    __syncthreads();
    if (t == 0) {
        if (totE <= EQCAP) {
            // insertion sort by index ascending, take first `need`
            for (int a = 1; a < (int)totE; ++a) {
                int key = eqbuf[a], c = a - 1;
                while (c >= 0 && eqbuf[c] > key) { eqbuf[c + 1] = eqbuf[c]; --c; }
                eqbuf[c + 1] = key;
            }
            for (int q = 0; q < need; ++q) out_j[totL + q] = eqbuf[q];
        } else {
            int taken = 0;
            for (int j = 0; j < NNODE && taken < need; ++j)
                if (__float_as_uint(sd[j]) == T) out_j[totL + taken++] = j;
        }
    }
    __syncthreads();

    if (t < KK) {
        int j = out_j[t];
        size_t eo = (size_t)gn * KK + t;
        idx_o[eo] = j;
        float r0 = __fsub_rn(xi0, xb[3 * j]);
        float r1 = __fsub_rn(xi1, xb[3 * j + 1]);
        float r2 = __fsub_rn(xi2, xb[3 * j + 2]);
        relk_o[eo * 3 + 0] = r0;
        relk_o[eo * 3 + 1] = r1;
        relk_o[eo * 3 + 2] = r2;
        distk_o[eo] = __fadd_rn(__fadd_rn(__fmul_rn(r0, r0), __fmul_rn(r1, r1)), __fmul_rn(r2, r2));
    }
}

// ---------------------------------------------------------------- edge MLP via MFMA + coors
// Block = 256 threads (4 waves), 2 nodes = 64 edges. Wave wn owns a 144-wide hidden slice,
// chunked over nb tiles {4,4,1} so live acc = 64 regs -> 2 blocks/CU co-resident.
__global__ __launch_bounds__(256, 2) void edge_kernel(
    const float* __restrict__ h, const float* __restrict__ x, const int* __restrict__ mask,
    const float* __restrict__ be1, const float* __restrict__ be2,
    const float* __restrict__ Wc1, const float* __restrict__ bc1,
    const float* __restrict__ Wc2, const float* __restrict__ bc2,
    const int* __restrict__ idx, const float* __restrict__ relk, const float* __restrict__ distk,
    const unsigned short* __restrict__ W1pack, const unsigned short* __restrict__ W2p2,
    float* __restrict__ m_i_out, float* __restrict__ coors_out)
{
    __shared__ unsigned short E2[64][168];    // h_j (0..127), dist (128), zeros (129..167)
    __shared__ unsigned short hi_s[2][136];   // h_i per node
    __shared__ float be1s[576];
    __shared__ int   j_s[64];
    __shared__ float cw_s[64];
    __shared__ float m_s4[4 * 64 * 16];       // per-wn partial m (pre-bias)
    __shared__ float m_sF[64 * 17];           // final silu'd m_ij

    const int t = threadIdx.x;
    const int gn0 = blockIdx.x * 2;           // 2 nodes per block
    const int b = gn0 >> 12;
    const int wn = t >> 6, lane = t & 63;
    const int l15 = lane & 15, g = lane >> 4;

    // ---- init
    if (t < 64) {
        size_t eo = (size_t)gn0 * KK + t;
        j_s[t] = idx[eo];
        float dv = distk[eo];
        ushort2* p = (ushort2*)&E2[t][128];
        p[0] = make_ushort2(f2bf(dv), 0);
        #pragma unroll
        for (int z = 1; z < 20; ++z) p[z] = make_ushort2(0, 0);
    }
    {
        int n = t >> 7, c = t & 127;
        hi_s[n][c] = f2bf(h[(size_t)(gn0 + n) * DD + c]);
    }
    for (int i2 = t; i2 < 576; i2 += 256) be1s[i2] = (i2 < 514) ? be1[i2] : 0.f;
    __syncthreads();

    // ---- gather h_j (bf16, packed pair converts)
    for (int q = t; q < 64 * 32; q += 256) {
        int e = q >> 5, d4 = q & 31;
        int j = j_s[e];
        float4 v = *(const float4*)(h + ((size_t)b * NNODE + j) * DD + d4 * 4);
        *(uint2*)&E2[e][d4 * 4] = make_uint2(pk2(v.x, v.y), pk2(v.z, v.w));
    }
    __syncthreads();

    const bf16x8* W1v = (const bf16x8*)W1pack;
    const bf16x8* W2v = (const bf16x8*)W2p2;
    int erow[4];
    #pragma unroll
    for (int et = 0; et < 4; ++et) erow[et] = et * 16 + l15;

    f32x4 acc2[4];
    #pragma unroll
    for (int et = 0; et < 4; ++et)
        #pragma unroll
        for (int r = 0; r < 4; ++r) acc2[et][r] = 0.f;

    // ---- chunks 0,1: 4 nb tiles each (64 hidden) -> GEMM1 + silu + 2 ks2-steps of GEMM2
    #pragma unroll
    for (int c = 0; c < 2; ++c) {
        f32x4 acc[4][4];
        #pragma unroll
        for (int nb = 0; nb < 4; ++nb)
            #pragma unroll
            for (int et = 0; et < 4; ++et)
                #pragma unroll
                for (int r = 0; r < 4; ++r) acc[nb][et][r] = 0.f;
        #pragma unroll
        for (int ks = 0; ks < 9; ++ks) {
            const bf16x8* wp = W1v + ((size_t)(ks * 36 + wn * 9 + c * 4)) * 64 + lane;
            bf16x8 afr[4];
            #pragma unroll
            for (int nb = 0; nb < 4; ++nb) afr[nb] = wp[nb * 64];
            bf16x8 bfr[4];
            if (ks < 4) {
                bf16x8 b0 = *(const bf16x8*)&hi_s[0][ks * 32 + 8 * g];
                bf16x8 b1 = *(const bf16x8*)&hi_s[1][ks * 32 + 8 * g];
                bfr[0] = b0; bfr[1] = b0; bfr[2] = b1; bfr[3] = b1;
            } else {
                #pragma unroll
                for (int et = 0; et < 4; ++et)
                    bfr[et] = *(const bf16x8*)&E2[erow[et]][(ks - 4) * 32 + 8 * g];
            }
            #pragma unroll
            for (int nb = 0; nb < 4; ++nb)
                #pragma unroll
                for (int et = 0; et < 4; ++et)
                    acc[nb][et] = __builtin_amdgcn_mfma_f32_16x16x32_bf16(afr[nb], bfr[et], acc[nb][et], 0, 0, 0);
        }
        // silu(acc + be1)
        #pragma unroll
        for (int nb = 0; nb < 4; ++nb) {
            f32x4 bv = *(const f32x4*)&be1s[wn * 144 + (c * 4 + nb) * 16 + 4 * g];
            #pragma unroll
            for (int et = 0; et < 4; ++et)
                #pragma unroll
                for (int r = 0; r < 4; ++r)
                    acc[nb][et][r] = silu_f(acc[nb][et][r] + bv[r]);
        }
        // GEMM2: ks2 = 2c, 2c+1
        #pragma unroll
        for (int qq = 0; qq < 2; ++qq) {
            int ks2 = 2 * c + qq;
            bf16x8 a2 = W2v[(size_t)(wn * 5 + ks2) * 64 + lane];
            #pragma unroll
            for (int et = 0; et < 4; ++et) {
                union { unsigned u[4]; bf16x8 v; } cv;
                cv.u[0] = pk2(acc[2 * qq][et][0], acc[2 * qq][et][1]);
                cv.u[1] = pk2(acc[2 * qq][et][2], acc[2 * qq][et][3]);
                cv.u[2] = pk2(acc[2 * qq + 1][et][0], acc[2 * qq + 1][et][1]);
                cv.u[3] = pk2(acc[2 * qq + 1][et][2], acc[2 * qq + 1][et][3]);
                acc2[et] = __builtin_amdgcn_mfma_f32_16x16x32_bf16(a2, cv.v, acc2[et], 0, 0, 0);
            }
        }
    }
    // ---- chunk 2: nb = 8 (last 16 hidden of slice), ks2 = 4
    {
        f32x4 acc8[4];
        #pragma unroll
        for (int et = 0; et < 4; ++et)
            #pragma unroll
            for (int r = 0; r < 4; ++r) acc8[et][r] = 0.f;
        #pragma unroll
        for (int ks = 0; ks < 9; ++ks) {
            bf16x8 af = W1v[((size_t)(ks * 36 + wn * 9 + 8)) * 64 + lane];
            bf16x8 bfr[4];
            if (ks < 4) {
                bf16x8 b0 = *(const bf16x8*)&hi_s[0][ks * 32 + 8 * g];
                bf16x8 b1 = *(const bf16x8*)&hi_s[1][ks * 32 + 8 * g];
                bfr[0] = b0; bfr[1] = b0; bfr[2] = b1; bfr[3] = b1;
            } else {
                #pragma unroll
                for (int et = 0; et < 4; ++et)
                    bfr[et] = *(const bf16x8*)&E2[erow[et]][(ks - 4) * 32 + 8 * g];
            }
            #pragma unroll
            for (int et = 0; et < 4; ++et)
                acc8[et] = __builtin_amdgcn_mfma_f32_16x16x32_bf16(af, bfr[et], acc8[et], 0, 0, 0);
        }
        f32x4 bv = *(const f32x4*)&be1s[wn * 144 + 128 + 4 * g];
        #pragma unroll
        for (int et = 0; et < 4; ++et)
            #pragma unroll
            for (int r = 0; r < 4; ++r)
                acc8[et][r] = silu_f(acc8[et][r] + bv[r]);
        bf16x8 a2 = W2v[(size_t)(wn * 5 + 4) * 64 + lane];
        #pragma unroll
        for (int et = 0; et < 4; ++et) {
            union { unsigned u[4]; bf16x8 v; } cv;
            cv.u[0] = pk2(acc8[et][0], acc8[et][1]);
            cv.u[1] = pk2(acc8[et][2], acc8[et][3]);
            cv.u[2] = 0; cv.u[3] = 0;
            acc2[et] = __builtin_amdgcn_mfma_f32_16x16x32_bf16(a2, cv.v, acc2[et], 0, 0, 0);
        }
    }
    // ---- store per-wn partial m (no atomics; disjoint slices)
    #pragma unroll
    for (int et = 0; et < 4; ++et)
        *(f32x4*)&m_s4[((wn * 64) + erow[et]) * 16 + 4 * g] = acc2[et];
    __syncthreads();

    // ---- reduce 4 slices + bias + silu
    #pragma unroll
    for (int i2 = t; i2 < 64 * 16; i2 += 256) {
        int e = i2 >> 4, f = i2 & 15;
        float s = m_s4[e * 16 + f] + m_s4[(64 + e) * 16 + f]
                + m_s4[(128 + e) * 16 + f] + m_s4[(192 + e) * 16 + f];
        m_sF[e * 17 + f] = silu_f(s + be2[f]);
    }
    __syncthreads();

    // ---- coordinate-weight MLP: 4 threads per edge
    {
        const int ee = t >> 2, q4 = t & 3;
        const int u0 = q4 * 16;
        float mm[16];
        #pragma unroll
        for (int f = 0; f < 16; ++f) mm[f] = m_sF[ee * 17 + f];
        float h2[16];
        {
            const float4* bp = (const float4*)(bc1 + u0);
            float4 b0 = bp[0], b1 = bp[1], b2v = bp[2], b3 = bp[3];
            h2[0]=b0.x; h2[1]=b0.y; h2[2]=b0.z; h2[3]=b0.w;
            h2[4]=b1.x; h2[5]=b1.y; h2[6]=b1.z; h2[7]=b1.w;
            h2[8]=b2v.x; h2[9]=b2v.y; h2[10]=b2v.z; h2[11]=b2v.w;
            h2[12]=b3.x; h2[13]=b3.y; h2[14]=b3.z; h2[15]=b3.w;
        }
        #pragma unroll
        for (int f = 0; f < 16; ++f) {
            const float4* wp = (const float4*)(Wc1 + (size_t)f * 64 + u0);
            float4 w0 = wp[0], w1 = wp[1], w2 = wp[2], w3 = wp[3];
            float v = mm[f];
            h2[0]  = fmaf(v, w0.x, h2[0]);  h2[1]  = fmaf(v, w0.y, h2[1]);
            h2[2]  = fmaf(v, w0.z, h2[2]);  h2[3]  = fmaf(v, w0.w, h2[3]);
            h2[4]  = fmaf(v, w1.x, h2[4]);  h2[5]  = fmaf(v, w1.y, h2[5]);
            h2[6]  = fmaf(v, w1.z, h2[6]);  h2[7]  = fmaf(v, w1.w, h2[7]);
            h2[8]  = fmaf(v, w2.x, h2[8]);  h2[9]  = fmaf(v, w2.y, h2[9]);
            h2[10] = fmaf(v, w2.z, h2[10]); h2[11] = fmaf(v, w2.w, h2[11]);
            h2[12] = fmaf(v, w3.x, h2[12]); h2[13] = fmaf(v, w3.y, h2[13]);
            h2[14] = fmaf(v, w3.z, h2[14]); h2[15] = fmaf(v, w3.w, h2[15]);
        }
        float cw = 0.f;
        const float4* cp = (const float4*)(Wc2 + u0);
        float4 c0 = cp[0], c1 = cp[1], c2 = cp[2], c3 = cp[3];
        const float wv[16] = {c0.x,c0.y,c0.z,c0.w, c1.x,c1.y,c1.z,c1.w,
                              c2.x,c2.y,c2.z,c2.w, c3.x,c3.y,c3.z,c3.w};
        #pragma unroll
        for (int r = 0; r < 16; ++r) cw = fmaf(silu_f(h2[r]), wv[r], cw);
        cw += __shfl_xor(cw, 1, 64);
        cw += __shfl_xor(cw, 2, 64);
        if (q4 == 0) {
            cw += bc2[0];
            int gnode = gn0 + (ee >> 5);
            int mi = mask[gnode];
            int mj = mask[b * NNODE + j_s[ee]];
            cw_s[ee] = (mi != 0 && mj != 0) ? cw : 0.f;
        }
    }
    __syncthreads();

    // ---- outputs
    if (t < 32) {
        int n = t >> 4, f = t & 15;
        float s = 0.f;
        #pragma unroll
        for (int k2 = 0; k2 < 32; ++k2) s += m_sF[(n * 32 + k2) * 17 + f];
        m_i_out[(size_t)(gn0 + n) * CFX + f] = s;
    } else if (t < 38) {
        int r = t - 32;
        int n = r / 3, c = r - n * 3;
        const float* rp = relk + ((size_t)gn0 * KK + n * 32) * 3 + c;
        float s = 0.f;
        #pragma unroll
        for (int k2 = 0; k2 < 32; ++k2) s = fmaf(cw_s[n * 32 + k2], rp[k2 * 3], s);
        coors_out[(size_t)(gn0 + n) * 3 + c] = s + x[(size_t)(gn0 + n) * 3 + c];
    }
}

// ---------------------------------------------------------------- node MLP (block = 4 nodes)
__global__ __launch_bounds__(256) void node_kernel(
    const float* __restrict__ h, const float* __restrict__ m_i,
    const float* __restrict__ Wn1, const float* __restrict__ bn1,
    const float* __restrict__ Wn2, const float* __restrict__ bn2,
    float* __restrict__ node_out) {
    __shared__ float nin[4][NINX + 1];
    __shared__ float hid[4][NHID + 1];
    const int t = threadIdx.x;
    const int gn0 = blockIdx.x * 4;
    for (int i = t; i < 4 * DD; i += 256) {
        int n = i >> 7, c = i & 127;
        nin[n][c] = h[(size_t)(gn0 + n) * DD + c];
    }
    if (t < 64) {
        int n = t >> 4, f = t & 15;
        nin[n][DD + f] = m_i[(size_t)(gn0 + n) * CFX + f];
    }
    __syncthreads();
    {
        const int u = t;
        float bv = bn1[u];
        float a0 = bv, a1 = bv, a2 = bv, a3 = bv;
        for (int c = 0; c < NINX; ++c) {
            float w = Wn1[(size_t)c * NHID + u];
            a0 = fmaf(nin[0][c], w, a0);
            a1 = fmaf(nin[1][c], w, a1);
            a2 = fmaf(nin[2][c], w, a2);
            a3 = fmaf(nin[3][c], w, a3);
        }
        hid[0][u] = silu_f(a0);
        hid[1][u] = silu_f(a1);
        hid[2][u] = silu_f(a2);
        hid[3][u] = silu_f(a3);
    }
    __syncthreads();
    {
        const int d = t & 127, n2 = t >> 7;
        float bv = bn2[d];
        float a0 = bv, a1 = bv;
        for (int uu = 0; uu < NHID; ++uu) {
            float w = Wn2[(size_t)uu * DD + d];
            a0 = fmaf(hid[n2][uu], w, a0);
            a1 = fmaf(hid[n2 + 2][uu], w, a1);
        }
        node_out[(size_t)(gn0 + n2) * DD + d] = a0 + nin[n2][d];
        node_out[(size_t)(gn0 + n2 + 2) * DD + d] = a1 + nin[n2 + 2][d];
    }
}

// ---------------------------------------------------------------- launch
extern "C" void kernel_launch(void* const* d_in, const int* in_sizes, int n_in,
                              void* d_out, int out_size, void* d_ws, size_t ws_size,
                              hipStream_t stream) {
    const float* h   = (const float*)d_in[0];
    const float* x   = (const float*)d_in[1];
    const int*   mask= (const int*)d_in[2];
    const float* We1 = (const float*)d_in[3];
    const float* be1 = (const float*)d_in[4];
    const float* We2 = (const float*)d_in[5];
    const float* be2 = (const float*)d_in[6];
    const float* Wc1 = (const float*)d_in[7];
    const float* bc1 = (const float*)d_in[8];
    const float* Wc2 = (const float*)d_in[9];
    const float* bc2 = (const float*)d_in[10];
    const float* Wn1 = (const float*)d_in[11];
    const float* bn1 = (const float*)d_in[12];
    const float* Wn2 = (const float*)d_in[13];
    const float* bn2 = (const float*)d_in[14];

    float* node_out  = (float*)d_out;
    float* coors_out = node_out + (size_t)BB * NNODE * DD;

    char* ws = (char*)d_ws;
    int*   idx    = (int*)ws;            ws += (size_t)BB * NNODE * KK * 4;
    float* relk   = (float*)ws;          ws += (size_t)BB * NNODE * KK * 3 * 4;
    float* distk  = (float*)ws;          ws += (size_t)BB * NNODE * KK * 4;
    float* m_i    = (float*)ws;          ws += (size_t)BB * NNODE * CFX * 4;
    unsigned short* W1pack = (unsigned short*)ws;  ws += (size_t)9 * 36 * 64 * 8 * 2;
    unsigned short* W2p2   = (unsigned short*)ws;  ws += (size_t)4 * 5 * 64 * 8 * 2;

    prep_kernel<<<256, 256, 0, stream>>>(We1, We2, W1pack, W2p2);
    knn_kernel<<<BB * NNODE, 256, 0, stream>>>(x, idx, relk, distk);
    edge_kernel<<<BB * NNODE / 2, 256, 0, stream>>>(h, x, mask, be1, be2, Wc1, bc1, Wc2, bc2,
                                                    idx, relk, distk, W1pack, W2p2,
                                                    m_i, coors_out);
    node_kernel<<<BB * NNODE / 4, 256, 0, stream>>>(h, m_i, Wn1, bn1, Wn2, bn2, node_out);
}